// Round 1
// baseline (4189.051 us; speedup 1.0000x reference)
//
#include <hip/hip_runtime.h>
#include <cmath>
#include <vector>
#include <algorithm>

// ---------------- constant table offsets (in floats) ----------------
enum : int {
  OFF_WIN  = 0,                  // 128 DH weights (b=64)
  OFF_WL1  = 128,                // 32  DH weights (b=16)
  OFF_WL2  = 160,                // 16  DH weights (b=8)
  OFF_DCOL = 176,                // 256*128: d^l_{m,0}(beta_in[k]) at (l^2+mi)*128+k
  OFF_D1   = OFF_DCOL + 32768,   // 174592: d^l(beta_l1[k]) at off3(l)*32 + k*(2l+1)^2 + r*(2l+1)+c
  OFF_D2   = OFF_D1 + 174592,    // 10880:  d^l(beta_l2[k]) at off3(l)*16 + k*(2l+1)^2 + r*(2l+1)+c
  OFF_PSI2 = OFF_D2 + 10880,     // 256*24 complex = 12288 floats
  OFF_PSI3 = OFF_PSI2 + 12288,   // 680*192 complex = 261120 floats
  CONST_TOTAL = OFF_PSI3 + 261120
};

// ---------------- workspace layout (bytes) ----------------
static constexpr size_t OFS_XF1  = 0;          // 16*128*31 c64 = 507904 B
static constexpr size_t OFS_FX   = 507904;     // 4096 c64   = 32768 B
static constexpr size_t OFS_FY1  = 540672;     // 16384 c64  = 131072 B
static constexpr size_t OFS_FX2  = 671744;     // 680*1024 c64 = 5570560 B
static constexpr size_t OFS_FY2  = 6242304;    // 680*8192 c64 = 44564480 B
static constexpr size_t OFS_FZ2  = 50806784;   // 680*2048 c64 = 11141120 B
static constexpr size_t OFS_FEAT = 61947904;   // 2048 f32 = 8192 B
static constexpr size_t WS_NEEDED = 61956096;

static inline int off3h(int l){ return (4*l*l*l - l)/3; }

// ---------------- host-side constant construction ----------------
namespace {

double fact_[32];
void init_fact(){ fact_[0]=1.0; for(int i=1;i<32;i++) fact_[i]=fact_[i-1]*i; }

// d^l_{m'm}(beta) = <l m'| e^{-i beta Jy} |l m>, row r = m'+l, col c = m+l
void wigner_d(int l, double beta, double* d){
  int n = 2*l+1;
  double cb = std::cos(beta*0.5), sb = std::sin(beta*0.5);
  for(int r=0;r<n;r++){ int mp = r-l;
    for(int c=0;c<n;c++){ int m = c-l;
      double f = std::sqrt(fact_[l+mp]*fact_[l-mp]*fact_[l+m]*fact_[l-m]);
      int s0 = std::max(0, m-mp), s1 = std::min(l+m, l-mp);
      double sum = 0;
      for(int s=s0;s<=s1;s++){
        double t = (((mp-m+s)&1)? -1.0 : 1.0)
                 / (fact_[l+m-s]*fact_[s]*fact_[mp-m+s]*fact_[l-mp-s]);
        t *= std::pow(cb, (double)(2*l+m-mp-2*s)) * std::pow(sb, (double)(mp-m+2*s));
        sum += t;
      }
      d[r*n+c] = f*sum;
    }
  }
}

void dh_weights(int b, double* w){
  for(int j=0;j<2*b;j++){
    double s = 0;
    for(int l=0;l<b;l++) s += std::sin((2.0*j+1)*(2.0*l+1)*M_PI/(4.0*b))/(2.0*l+1);
    w[j] = (2.0/b)*std::sin(M_PI*(2.0*j+1)/(4.0*b))*s;
  }
}

float* g_const = nullptr;

struct ConstInit {
  ConstInit(){
    init_fact();
    std::vector<float> h((size_t)CONST_TOTAL, 0.0f);
    std::vector<double> tmp(31*31);
    { std::vector<double> w(128); dh_weights(64, w.data()); for(int i=0;i<128;i++) h[OFF_WIN+i]=(float)w[i]; }
    { std::vector<double> w(32);  dh_weights(16, w.data()); for(int i=0;i<32;i++)  h[OFF_WL1+i]=(float)w[i]; }
    { std::vector<double> w(16);  dh_weights(8,  w.data()); for(int i=0;i<16;i++)  h[OFF_WL2+i]=(float)w[i]; }
    // DCOL: betas_in[k] = pi(2k+1)/256
    for(int l=0;l<16;l++){ int n=2*l+1;
      for(int k=0;k<128;k++){
        wigner_d(l, M_PI*(2.0*k+1)/256.0, tmp.data());
        for(int mi=0;mi<n;mi++) h[OFF_DCOL + (size_t)(l*l+mi)*128 + k] = (float)tmp[mi*n + l];
      }
    }
    // D1: betas_l1[k] = pi(2k+1)/64, k<32, l<16
    for(int l=0;l<16;l++){ int n=2*l+1;
      for(int k=0;k<32;k++){
        wigner_d(l, M_PI*(2.0*k+1)/64.0, tmp.data());
        for(int t=0;t<n*n;t++) h[OFF_D1 + (size_t)off3h(l)*32 + (size_t)k*n*n + t] = (float)tmp[t];
      }
    }
    // D2: betas_l2[k] = pi(2k+1)/32, k<16, l<8
    for(int l=0;l<8;l++){ int n=2*l+1;
      for(int k=0;k<16;k++){
        wigner_d(l, M_PI*(2.0*k+1)/32.0, tmp.data());
        for(int t=0;t<n*n;t++) h[OFF_D2 + (size_t)off3h(l)*16 + (size_t)k*n*n + t] = (float)tmp[t];
      }
    }
    // PSI2: s2 grid: beta_i=(i+1)pi/24 i<3, alpha_j=2pi j/8; g=i*8+j
    for(int l=0;l<16;l++){ int n=2*l+1;
      for(int i=0;i<3;i++){
        wigner_d(l, (i+1)*(M_PI/8.0)/3.0, tmp.data());
        for(int j=0;j<8;j++){
          double alpha = 2.0*M_PI*j/8.0;
          int g = i*8+j;
          for(int mi=0;mi<n;mi++){
            double d = tmp[mi*n + l];
            double th = (double)(mi-l)*alpha;
            size_t base = OFF_PSI2 + ((size_t)(l*l+mi)*24 + g)*2;
            h[base+0] = (float)( d*std::cos(th));
            h[base+1] = (float)(-d*std::sin(th));
          }
        }
      }
    }
    // PSI3: so3 grid: g=(i*8+j)*8+kk, gamma = 2pi kk/8 - alpha
    for(int l=0;l<8;l++){ int n=2*l+1;
      for(int i=0;i<3;i++){
        wigner_d(l, (i+1)*(M_PI/8.0)/3.0, tmp.data());
        for(int j=0;j<8;j++){
          double alpha = 2.0*M_PI*j/8.0;
          for(int kk=0;kk<8;kk++){
            double gamma = 2.0*M_PI*kk/8.0 - alpha;
            int g = (i*8+j)*8+kk;
            for(int mi=0;mi<n;mi++) for(int ni=0;ni<n;ni++){
              double d = tmp[mi*n+ni];
              double th = (double)(mi-l)*alpha + (double)(ni-l)*gamma;
              size_t base = OFF_PSI3 + (((size_t)off3h(l)+ (size_t)mi*n+ni)*192 + g)*2;
              h[base+0] = (float)( d*std::cos(th));
              h[base+1] = (float)(-d*std::sin(th));
            }
          }
        }
      }
    }
    hipMalloc((void**)&g_const, sizeof(float)*(size_t)CONST_TOTAL);
    hipMemcpy(g_const, h.data(), sizeof(float)*(size_t)CONST_TOTAL, hipMemcpyHostToDevice);
  }
};
ConstInit g_init_;

} // namespace

// ---------------- device helpers ----------------
__device__ __forceinline__ int off3d(int l){ return (4*l*l*l - l)/3; }
constexpr float TWO_PI_F = 6.28318530717958647692f;

// K1: xf1[b,k,m] = sum_a x[b,0,k,a] e^{-2pi i m a/128}, m in [-15,15]
__global__ void k_fft_alpha(const float* __restrict__ x, float2* __restrict__ xf1){
  __shared__ float row[128];
  __shared__ float2 w128[128];
  int r = blockIdx.x;         // b*128+k
  int t = threadIdx.x;        // 128 threads
  row[t] = x[(size_t)r*128 + t];
  float ang = (TWO_PI_F/128.0f)*t;
  w128[t] = make_float2(cosf(ang), sinf(ang));
  __syncthreads();
  if(t < 31){
    int m = t - 15;
    float2 acc = make_float2(0.f,0.f);
    for(int a=0;a<128;a++){
      float2 w = w128[(m*a)&127];
      acc.x += row[a]*w.x;
      acc.y -= row[a]*w.y;
    }
    xf1[(size_t)r*31 + t] = acc;
  }
}

// K2: Fx[c2= l^2+mi][b] = (2pi/128) sum_k W_IN[k] DCOL[c2][k] xf1[b,k,m]
__global__ void k_fx(const float* __restrict__ cst, const float2* __restrict__ xf1,
                     float2* __restrict__ FxP){
  int idx = blockIdx.x*blockDim.x + threadIdx.x;    // 4096
  int c2 = idx >> 4, b = idx & 15;
  int l = 0; while((l+1)*(l+1) <= c2) l++;
  int m = (c2 - l*l) - l;
  const float* W  = cst + OFF_WIN;
  const float* DC = cst + OFF_DCOL + (size_t)c2*128;
  float2 acc = make_float2(0.f,0.f);
  for(int k=0;k<128;k++){
    float wv = W[k]*DC[k];
    float2 xv = xf1[((size_t)b*128+k)*31 + (m+15)];
    acc.x += wv*xv.x; acc.y += wv*xv.y;
  }
  float s = TWO_PI_F/128.0f;
  FxP[(size_t)c2*16+b] = make_float2(acc.x*s, acc.y*s);
}

// K3: Fy1[c2][o] = sum_g w1[o,g] * PSI2[c2][g]
__global__ void k_fy1(const float* __restrict__ cst, const float* __restrict__ w1,
                      float2* __restrict__ FyP){
  int idx = blockIdx.x*blockDim.x + threadIdx.x;    // 16384
  int c2 = idx >> 6, o = idx & 63;
  const float2* psi = (const float2*)(cst + OFF_PSI2) + (size_t)c2*24;
  const float* w1r = w1 + (size_t)o*24;
  float2 acc = make_float2(0.f,0.f);
  for(int g=0;g<24;g++){
    float wv = w1r[g];
    float2 p = psi[g];
    acc.x += wv*p.x; acc.y += wv*p.y;
  }
  FyP[(size_t)c2*64+o] = acc;
}

// K5: per-slice (b,o,k): S(m,n) -> idft2 -> relu -> dft2 -> atomic accumulate into Fx2
__global__ void __launch_bounds__(256) k_slice1(const float* __restrict__ cst,
                                                const float2* __restrict__ FxP,
                                                const float2* __restrict__ FyP,
                                                float2* __restrict__ Fx2P){
  __shared__ float2 S[31*32];
  __shared__ float2 T[31*32];
  __shared__ float  y[32*32];
  __shared__ float2 T2[15*32];
  __shared__ float2 w32[32];
  int sid = blockIdx.x;
  int b = sid >> 11, o = (sid >> 5) & 63, k = sid & 31;
  int tid = threadIdx.x;
  if(tid < 32){ float ang = (TWO_PI_F/32.0f)*tid; w32[tid] = make_float2(cosf(ang), sinf(ang)); }
  __syncthreads();
  const float* D1 = cst + OFF_D1;
  // stage 1: S[m,n] = sum_l (2l+1) d_l[k,m,n] * Fx[l,m,b]*conj(Fy[l,n,o])
  for(int t=tid; t<961; t+=256){
    int miq = t/31, niq = t%31;
    int m = miq-15, n = niq-15;
    int am = m<0?-m:m, an = n<0?-n:n;
    int lmin = am>an?am:an;
    float2 acc = make_float2(0.f,0.f);
    for(int l=lmin;l<16;l++){
      int c = 2*l+1; int o3 = off3d(l);
      float dv = D1[(size_t)o3*32 + (size_t)k*c*c + (m+l)*c + (n+l)];
      float2 fx = FxP[(size_t)(l*l + (m+l))*16 + b];
      float2 fy = FyP[(size_t)(l*l + (n+l))*64 + o];
      // fz = fx * conj(fy)
      float2 fz = make_float2(fx.x*fy.x + fx.y*fy.y, fx.y*fy.x - fx.x*fy.y);
      float wgt = (float)(2*l+1)*dv;
      acc.x += wgt*fz.x; acc.y += wgt*fz.y;
    }
    S[miq*32+niq] = acc;
  }
  __syncthreads();
  // stage 2: T[m,c] = sum_n S[m,n] e^{+2pi i n c/32}
  for(int t=tid; t<992; t+=256){
    int miq = t >> 5, c = t & 31;
    float2 acc = make_float2(0.f,0.f);
    for(int niq=0;niq<31;niq++){
      float2 sv = S[miq*32+niq];
      float2 w = w32[((niq-15)*c)&31];
      acc.x += sv.x*w.x - sv.y*w.y;
      acc.y += sv.x*w.y + sv.y*w.x;
    }
    T[miq*32+c] = acc;
  }
  __syncthreads();
  // stage 3: y[a,c] = relu(Re sum_m T[m,c] e^{+2pi i m a/32})
  for(int t=tid; t<1024; t+=256){
    int a = t >> 5, c = t & 31;
    float acc = 0.f;
    for(int miq=0;miq<31;miq++){
      float2 tv = T[miq*32+c];
      float2 w = w32[((miq-15)*a)&31];
      acc += tv.x*w.x - tv.y*w.y;
    }
    y[t] = acc > 0.f ? acc : 0.f;
  }
  __syncthreads();
  // stage 4: T2[mp,c] = sum_a y[a,c] e^{-2pi i mp a/32}, mp in [-7,7]
  for(int t=tid; t<480; t+=256){
    int mpq = t >> 5, c = t & 31;
    float2 acc = make_float2(0.f,0.f);
    for(int a=0;a<32;a++){
      float yv = y[a*32+c];
      float2 w = w32[((mpq-7)*a)&31];
      acc.x += yv*w.x; acc.y -= yv*w.y;
    }
    T2[mpq*32+c] = acc;
  }
  __syncthreads();
  // stage 5: Xf[mp,np] = (1/1024) sum_c T2[mp,c] e^{-2pi i np c/32}; scatter into Fx2
  const float* WL1 = cst + OFF_WL1;
  float wk = WL1[k]*TWO_PI_F;
  for(int t=tid; t<225; t+=256){
    int mpq = t/15, npq = t%15;
    int mp = mpq-7, np = npq-7;
    float2 acc = make_float2(0.f,0.f);
    for(int c=0;c<32;c++){
      float2 tv = T2[mpq*32+c];
      float2 w = w32[(np*c)&31];
      acc.x += tv.x*w.x + tv.y*w.y;
      acc.y += tv.y*w.x - tv.x*w.y;
    }
    acc.x *= (1.0f/1024.0f); acc.y *= (1.0f/1024.0f);
    int am = mp<0?-mp:mp, an = np<0?-np:np;
    int lmin = am>an?am:an;
    for(int l=lmin;l<8;l++){
      int c = 2*l+1; int o3 = off3d(l);
      float dv = D1[(size_t)o3*32 + (size_t)k*c*c + (mp+l)*c + (np+l)];
      float g = wk*dv;
      float* dst = (float*)(Fx2P + ((size_t)o3 + (mp+l)*c + (np+l))*1024 + (size_t)b*64 + o);
      atomicAdd(dst,   g*acc.x);
      atomicAdd(dst+1, g*acc.y);
    }
  }
}

// K7: Fy2[coef][i,o] = sum_g w2[i,o,g] * PSI3[coef][g]
__global__ void k_fy2(const float* __restrict__ cst, const float* __restrict__ w2,
                      float2* __restrict__ Fy2P){
  int idx = blockIdx.x*256 + threadIdx.x;   // 680*8192
  int coef = idx >> 13, io = idx & 8191;
  const float2* psi = (const float2*)(cst + OFF_PSI3) + (size_t)coef*192;
  const float* w2r = w2 + (size_t)io*192;
  float2 acc = make_float2(0.f,0.f);
  for(int g=0;g<192;g++){
    float wv = w2r[g];
    float2 p = psi[g];
    acc.x += wv*p.x; acc.y += wv*p.y;
  }
  Fy2P[(size_t)coef*8192 + io] = acc;
}

// K8: Fz2[l][m,n,b,o] = sum_{kk,i} Fx2[l][m,kk,b,i] * conj(Fy2[l][n,kk,i,o])
__global__ void k_fz2(const float2* __restrict__ Fx2P, const float2* __restrict__ Fy2P,
                      float2* __restrict__ Fz2P){
  int idx = blockIdx.x*256 + threadIdx.x;   // 680*2048
  int coef = idx >> 11, bo = idx & 2047;
  int b = bo >> 7, o = bo & 127;
  int l = 0; while(l<7 && off3d(l+1) <= coef) l++;
  int c = 2*l+1; int o3 = off3d(l);
  int p = coef - o3; int mi = p/c, ni = p%c;
  float2 acc = make_float2(0.f,0.f);
  for(int kk=0;kk<c;kk++){
    const float2* fxr = Fx2P + ((size_t)o3 + mi*c + kk)*1024 + (size_t)b*64;
    const float2* fyr = Fy2P + ((size_t)o3 + ni*c + kk)*8192 + o;
    for(int i=0;i<64;i++){
      float2 a  = fxr[i];
      float2 bb = fyr[(size_t)i*128];
      acc.x += a.x*bb.x + a.y*bb.y;
      acc.y += a.y*bb.x - a.x*bb.y;
    }
  }
  Fz2P[(size_t)coef*2048 + bo] = acc;
}

// K9: per (b,o): loop k2: S2 -> idft2(16x16) -> relu -> weighted mean -> feat[b,o]
__global__ void __launch_bounds__(256) k_slice2(const float* __restrict__ cst,
                                                const float2* __restrict__ Fz2P,
                                                float* __restrict__ featP){
  __shared__ float2 FzL[680];
  __shared__ float2 S2[225];
  __shared__ float2 TA[240];
  __shared__ float2 w16[16];
  __shared__ float red[256];
  int bo = blockIdx.x;
  int tid = threadIdx.x;
  if(tid < 16){ float ang = (TWO_PI_F/16.0f)*tid; w16[tid] = make_float2(cosf(ang), sinf(ang)); }
  for(int t=tid; t<680; t+=256) FzL[t] = Fz2P[(size_t)t*2048 + bo];
  __syncthreads();
  const float* D2  = cst + OFF_D2;
  const float* WL2 = cst + OFF_WL2;
  float part = 0.f;
  for(int k2=0;k2<16;k2++){
    if(tid < 225){
      int mi = tid/15, ni = tid%15;
      int m = mi-7, n = ni-7;
      int am = m<0?-m:m, an = n<0?-n:n;
      int lmin = am>an?am:an;
      float2 acc = make_float2(0.f,0.f);
      for(int l=lmin;l<8;l++){
        int c = 2*l+1; int o3 = off3d(l);
        float dv = D2[(size_t)o3*16 + (size_t)k2*c*c + (m+l)*c + (n+l)];
        float wgt = (float)(2*l+1)*dv;
        float2 fz = FzL[o3 + (m+l)*c + (n+l)];
        acc.x += wgt*fz.x; acc.y += wgt*fz.y;
      }
      S2[tid] = acc;
    }
    __syncthreads();
    if(tid < 240){
      int mi = tid >> 4, c = tid & 15;
      float2 acc = make_float2(0.f,0.f);
      for(int ni=0;ni<15;ni++){
        float2 sv = S2[mi*15+ni];
        float2 w = w16[((ni-7)*c)&15];
        acc.x += sv.x*w.x - sv.y*w.y;
        acc.y += sv.x*w.y + sv.y*w.x;
      }
      TA[mi*16+c] = acc;
    }
    __syncthreads();
    {
      int a = tid >> 4, c = tid & 15;
      float acc = 0.f;
      for(int mi=0;mi<15;mi++){
        float2 tv = TA[mi*16+c];
        float2 w = w16[((mi-7)*a)&15];
        acc += tv.x*w.x - tv.y*w.y;
      }
      if(acc > 0.f) part += WL2[k2]*acc;
    }
    __syncthreads();
  }
  red[tid] = part;
  __syncthreads();
  for(int s=128;s>0;s>>=1){ if(tid<s) red[tid]+=red[tid+s]; __syncthreads(); }
  if(tid==0) featP[bo] = red[0]*(1.0f/256.0f);
}

// K10: out[b,j] = sum_o feat[b,o]*lin_w[j,o] + lin_b[j]
__global__ void k_out(const float* __restrict__ featP, const float* __restrict__ lin_w,
                      const float* __restrict__ lin_b, float* __restrict__ out){
  int t = threadIdx.x;
  if(t < 160){
    int b = t/10, j = t%10;
    float acc = lin_b[j];
    for(int o=0;o<128;o++) acc += featP[b*128+o]*lin_w[j*128+o];
    out[t] = acc;
  }
}

extern "C" void kernel_launch(void* const* d_in, const int* in_sizes, int n_in,
                              void* d_out, int out_size, void* d_ws, size_t ws_size,
                              hipStream_t stream){
  const float* x     = (const float*)d_in[0];
  const float* w1    = (const float*)d_in[1];
  const float* w2    = (const float*)d_in[2];
  const float* lin_w = (const float*)d_in[3];
  const float* lin_b = (const float*)d_in[4];
  float* out = (float*)d_out;
  if(ws_size < WS_NEEDED) return;  // will show as wrong answer, flags ws shortfall
  char* ws = (char*)d_ws;
  float2* xf1  = (float2*)(ws + OFS_XF1);
  float2* FxP  = (float2*)(ws + OFS_FX);
  float2* FyP  = (float2*)(ws + OFS_FY1);
  float2* Fx2P = (float2*)(ws + OFS_FX2);
  float2* Fy2P = (float2*)(ws + OFS_FY2);
  float2* Fz2P = (float2*)(ws + OFS_FZ2);
  float*  featP= (float*)(ws + OFS_FEAT);
  const float* cst = g_const;

  hipMemsetAsync(Fx2P, 0, (size_t)680*1024*sizeof(float2), stream);
  k_fft_alpha<<<2048, 128, 0, stream>>>(x, xf1);
  k_fx      <<<16,   256, 0, stream>>>(cst, xf1, FxP);
  k_fy1     <<<64,   256, 0, stream>>>(cst, w1, FyP);
  k_slice1  <<<32768,256, 0, stream>>>(cst, FxP, FyP, Fx2P);
  k_fy2     <<<21760,256, 0, stream>>>(cst, w2, Fy2P);
  k_fz2     <<<5440, 256, 0, stream>>>(Fx2P, Fy2P, Fz2P);
  k_slice2  <<<2048, 256, 0, stream>>>(cst, Fz2P, featP);
  k_out     <<<1,    256, 0, stream>>>(featP, lin_w, lin_b, out);
}

// Round 2
// 1866.745 us; speedup vs baseline: 2.2440x; 2.2440x over previous
//
#include <hip/hip_runtime.h>
#include <cmath>
#include <vector>
#include <algorithm>

// ---------------- constant table offsets (in floats) ----------------
enum : int {
  OFF_WIN  = 0,                  // 128 DH weights (b=64)
  OFF_WL1  = 128,                // 32  DH weights (b=16)
  OFF_WL2  = 160,                // 16  DH weights (b=8)
  OFF_DCOL = 176,                // 256*128: d^l_{m,0}(beta_in[k]) at (l^2+mi)*128+k
  OFF_D1   = OFF_DCOL + 32768,   // 174592: d^l(beta_l1[k]) at off3(l)*32 + k*(2l+1)^2 + r*(2l+1)+c
  OFF_D2   = OFF_D1 + 174592,    // 10880:  d^l(beta_l2[k]) at off3(l)*16 + k*(2l+1)^2 + r*(2l+1)+c
  OFF_PSI2 = OFF_D2 + 10880,     // 256*24 complex = 12288 floats
  OFF_PSI3 = OFF_PSI2 + 12288,   // 680*192 complex = 261120 floats
  CONST_TOTAL = OFF_PSI3 + 261120
};

// ---------------- workspace layout (bytes) ----------------
static constexpr size_t OFS_XF1  = 0;          // 16*128*31 c64 = 507904 B
static constexpr size_t OFS_FX   = 507904;     // 4096 c64   = 32768 B
static constexpr size_t OFS_FY1  = 540672;     // 16384 c64  = 131072 B
static constexpr size_t OFS_FX2  = 671744;     // 680*1024 c64 = 5570560 B
static constexpr size_t OFS_FY2  = 6242304;    // 680*8192 c64 = 44564480 B
static constexpr size_t OFS_FZ2  = 50806784;   // 680*2048 c64 = 11141120 B
static constexpr size_t OFS_W2T  = OFS_FZ2;    // 8192*192 f32 = 6291456 B (dead before Fz2 written)
static constexpr size_t OFS_FEAT = 61947904;   // 2048 f32 = 8192 B
static constexpr size_t WS_NEEDED = 61956096;

static inline int off3h(int l){ return (4*l*l*l - l)/3; }

// ---------------- host-side constant construction ----------------
namespace {

double fact_[32];
void init_fact(){ fact_[0]=1.0; for(int i=1;i<32;i++) fact_[i]=fact_[i-1]*i; }

// d^l_{m'm}(beta) = <l m'| e^{-i beta Jy} |l m>, row r = m'+l, col c = m+l
void wigner_d(int l, double beta, double* d){
  int n = 2*l+1;
  double cb = std::cos(beta*0.5), sb = std::sin(beta*0.5);
  for(int r=0;r<n;r++){ int mp = r-l;
    for(int c=0;c<n;c++){ int m = c-l;
      double f = std::sqrt(fact_[l+mp]*fact_[l-mp]*fact_[l+m]*fact_[l-m]);
      int s0 = std::max(0, m-mp), s1 = std::min(l+m, l-mp);
      double sum = 0;
      for(int s=s0;s<=s1;s++){
        double t = (((mp-m+s)&1)? -1.0 : 1.0)
                 / (fact_[l+m-s]*fact_[s]*fact_[mp-m+s]*fact_[l-mp-s]);
        t *= std::pow(cb, (double)(2*l+m-mp-2*s)) * std::pow(sb, (double)(mp-m+2*s));
        sum += t;
      }
      d[r*n+c] = f*sum;
    }
  }
}

void dh_weights(int b, double* w){
  for(int j=0;j<2*b;j++){
    double s = 0;
    for(int l=0;l<b;l++) s += std::sin((2.0*j+1)*(2.0*l+1)*M_PI/(4.0*b))/(2.0*l+1);
    w[j] = (2.0/b)*std::sin(M_PI*(2.0*j+1)/(4.0*b))*s;
  }
}

float* g_const = nullptr;

struct ConstInit {
  ConstInit(){
    init_fact();
    std::vector<float> h((size_t)CONST_TOTAL, 0.0f);
    std::vector<double> tmp(31*31);
    { std::vector<double> w(128); dh_weights(64, w.data()); for(int i=0;i<128;i++) h[OFF_WIN+i]=(float)w[i]; }
    { std::vector<double> w(32);  dh_weights(16, w.data()); for(int i=0;i<32;i++)  h[OFF_WL1+i]=(float)w[i]; }
    { std::vector<double> w(16);  dh_weights(8,  w.data()); for(int i=0;i<16;i++)  h[OFF_WL2+i]=(float)w[i]; }
    for(int l=0;l<16;l++){ int n=2*l+1;
      for(int k=0;k<128;k++){
        wigner_d(l, M_PI*(2.0*k+1)/256.0, tmp.data());
        for(int mi=0;mi<n;mi++) h[OFF_DCOL + (size_t)(l*l+mi)*128 + k] = (float)tmp[mi*n + l];
      }
    }
    for(int l=0;l<16;l++){ int n=2*l+1;
      for(int k=0;k<32;k++){
        wigner_d(l, M_PI*(2.0*k+1)/64.0, tmp.data());
        for(int t=0;t<n*n;t++) h[OFF_D1 + (size_t)off3h(l)*32 + (size_t)k*n*n + t] = (float)tmp[t];
      }
    }
    for(int l=0;l<8;l++){ int n=2*l+1;
      for(int k=0;k<16;k++){
        wigner_d(l, M_PI*(2.0*k+1)/32.0, tmp.data());
        for(int t=0;t<n*n;t++) h[OFF_D2 + (size_t)off3h(l)*16 + (size_t)k*n*n + t] = (float)tmp[t];
      }
    }
    for(int l=0;l<16;l++){ int n=2*l+1;
      for(int i=0;i<3;i++){
        wigner_d(l, (i+1)*(M_PI/8.0)/3.0, tmp.data());
        for(int j=0;j<8;j++){
          double alpha = 2.0*M_PI*j/8.0;
          int g = i*8+j;
          for(int mi=0;mi<n;mi++){
            double d = tmp[mi*n + l];
            double th = (double)(mi-l)*alpha;
            size_t base = OFF_PSI2 + ((size_t)(l*l+mi)*24 + g)*2;
            h[base+0] = (float)( d*std::cos(th));
            h[base+1] = (float)(-d*std::sin(th));
          }
        }
      }
    }
    for(int l=0;l<8;l++){ int n=2*l+1;
      for(int i=0;i<3;i++){
        wigner_d(l, (i+1)*(M_PI/8.0)/3.0, tmp.data());
        for(int j=0;j<8;j++){
          double alpha = 2.0*M_PI*j/8.0;
          for(int kk=0;kk<8;kk++){
            double gamma = 2.0*M_PI*kk/8.0 - alpha;
            int g = (i*8+j)*8+kk;
            for(int mi=0;mi<n;mi++) for(int ni=0;ni<n;ni++){
              double d = tmp[mi*n+ni];
              double th = (double)(mi-l)*alpha + (double)(ni-l)*gamma;
              size_t base = OFF_PSI3 + (((size_t)off3h(l)+ (size_t)mi*n+ni)*192 + g)*2;
              h[base+0] = (float)( d*std::cos(th));
              h[base+1] = (float)(-d*std::sin(th));
            }
          }
        }
      }
    }
    hipMalloc((void**)&g_const, sizeof(float)*(size_t)CONST_TOTAL);
    hipMemcpy(g_const, h.data(), sizeof(float)*(size_t)CONST_TOTAL, hipMemcpyHostToDevice);
  }
};
ConstInit g_init_;

} // namespace

// ---------------- device helpers ----------------
__device__ __forceinline__ int off3d(int l){ return (4*l*l*l - l)/3; }
constexpr float TWO_PI_F = 6.28318530717958647692f;

// K1: xf1[b,k,m] = sum_a x[b,0,k,a] e^{-2pi i m a/128}, m in [-15,15]
__global__ void k_fft_alpha(const float* __restrict__ x, float2* __restrict__ xf1){
  __shared__ float row[128];
  __shared__ float2 w128[128];
  int r = blockIdx.x;
  int t = threadIdx.x;
  row[t] = x[(size_t)r*128 + t];
  float ang = (TWO_PI_F/128.0f)*t;
  w128[t] = make_float2(cosf(ang), sinf(ang));
  __syncthreads();
  if(t < 31){
    int m = t - 15;
    float2 acc = make_float2(0.f,0.f);
    for(int a=0;a<128;a++){
      float2 w = w128[(m*a)&127];
      acc.x += row[a]*w.x;
      acc.y -= row[a]*w.y;
    }
    xf1[(size_t)r*31 + t] = acc;
  }
}

// K2: Fx[c2][b]
__global__ void k_fx(const float* __restrict__ cst, const float2* __restrict__ xf1,
                     float2* __restrict__ FxP){
  int idx = blockIdx.x*blockDim.x + threadIdx.x;    // 4096
  int c2 = idx >> 4, b = idx & 15;
  int l = 0; while((l+1)*(l+1) <= c2) l++;
  int m = (c2 - l*l) - l;
  const float* W  = cst + OFF_WIN;
  const float* DC = cst + OFF_DCOL + (size_t)c2*128;
  float2 acc = make_float2(0.f,0.f);
  for(int k=0;k<128;k++){
    float wv = W[k]*DC[k];
    float2 xv = xf1[((size_t)b*128+k)*31 + (m+15)];
    acc.x += wv*xv.x; acc.y += wv*xv.y;
  }
  float s = TWO_PI_F/128.0f;
  FxP[(size_t)c2*16+b] = make_float2(acc.x*s, acc.y*s);
}

// K3: Fy1[c2][o]
__global__ void k_fy1(const float* __restrict__ cst, const float* __restrict__ w1,
                      float2* __restrict__ FyP){
  int idx = blockIdx.x*blockDim.x + threadIdx.x;    // 16384
  int c2 = idx >> 6, o = idx & 63;
  const float2* psi = (const float2*)(cst + OFF_PSI2) + (size_t)c2*24;
  const float* w1r = w1 + (size_t)o*24;
  float2 acc = make_float2(0.f,0.f);
  for(int g=0;g<24;g++){
    float wv = w1r[g];
    float2 p = psi[g];
    acc.x += wv*p.x; acc.y += wv*p.y;
  }
  FyP[(size_t)c2*64+o] = acc;
}

// K4: fused first conv: one block per (b,o), full k-loop, Fx2 accumulated in LDS, no atomics.
__global__ void __launch_bounds__(256) k_conv1(const float* __restrict__ cst,
                                               const float2* __restrict__ FxP,
                                               const float2* __restrict__ FyP,
                                               float2* __restrict__ Fx2P){
  __shared__ __align__(16) char ldsraw[65216];
  float2* fz   = (float2*)ldsraw;            // 5456 c64 (43648 B)
  float2* S    = (float2*)(ldsraw + 43648);  // 992 c64  (7936 B)  [alias: FxL/FyL, y]
  float2* T    = (float2*)(ldsraw + 51584);  // 992 c64  (7936 B)  [alias: T2]
  float2* acc2 = (float2*)(ldsraw + 59520);  // 680 c64  (5440 B)
  float2* w32  = (float2*)(ldsraw + 64960);  // 32 c64   (256 B)
  float2* FxL  = S;            // 256 c64 (staging, dead after fz built)
  float2* FyL  = S + 256;      // 256 c64
  float*  y    = (float*)S;    // 1024 f32 (stage3 output, S dead by then)
  float2* T2   = T;            // 480 c64  (stage4 output, T dead by then)

  int b = blockIdx.x >> 6, o = blockIdx.x & 63;
  int tid = threadIdx.x;
  if(tid < 32){ float ang = (TWO_PI_F/32.0f)*tid; w32[tid] = make_float2(cosf(ang), sinf(ang)); }
  FxL[tid] = FxP[(size_t)tid*16 + b];
  FyL[tid] = FyP[(size_t)tid*64 + o];
  for(int t=tid; t<680; t+=256) acc2[t] = make_float2(0.f,0.f);
  __syncthreads();
  // fz[l,m,n] = Fx[l,m,b] * conj(Fy[l,n,o]) — computed once, reused over all 32 k
  for(int l=0;l<16;l++){
    int c = 2*l+1, o3 = off3d(l), n2 = c*c, l2 = l*l;
    for(int t=tid; t<n2; t+=256){
      int mi = t/c, ni = t%c;
      float2 fx = FxL[l2+mi], fy = FyL[l2+ni];
      fz[o3+t] = make_float2(fx.x*fy.x + fx.y*fy.y, fx.y*fy.x - fx.x*fy.y);
    }
  }
  __syncthreads();
  const float* D1  = cst + OFF_D1;
  const float* WL1 = cst + OFF_WL1;
  for(int k=0;k<32;k++){
    // stage1: S[m,n] = sum_l (2l+1) d_l[k,m,n] fz[l,m,n]
    for(int t=tid; t<961; t+=256){
      int miq = t/31, niq = t%31;
      int m = miq-15, n = niq-15;
      int am = m<0?-m:m, an = n<0?-n:n;
      int lmin = am>an?am:an;
      float2 acc = make_float2(0.f,0.f);
      for(int l=lmin;l<16;l++){
        int c = 2*l+1; int o3 = off3d(l);
        int idx = (m+l)*c + (n+l);
        float dv = D1[(size_t)o3*32 + (size_t)k*c*c + idx];
        float2 fzv = fz[o3 + idx];
        float wgt = (float)(2*l+1)*dv;
        acc.x += wgt*fzv.x; acc.y += wgt*fzv.y;
      }
      S[miq*32+niq] = acc;
    }
    __syncthreads();
    // stage2: T[m,c] = sum_n S[m,n] e^{+2pi i n c/32}
    for(int t=tid; t<992; t+=256){
      int miq = t >> 5, c = t & 31;
      float2 acc = make_float2(0.f,0.f);
      for(int niq=0;niq<31;niq++){
        float2 sv = S[miq*32+niq];
        float2 w = w32[((niq-15)*c)&31];
        acc.x += sv.x*w.x - sv.y*w.y;
        acc.y += sv.x*w.y + sv.y*w.x;
      }
      T[miq*32+c] = acc;
    }
    __syncthreads();
    // stage3: y[a,c] = relu(Re sum_m T[m,c] e^{+2pi i m a/32})  (y aliases S)
    for(int t=tid; t<1024; t+=256){
      int a = t >> 5, c = t & 31;
      float acc = 0.f;
      for(int miq=0;miq<31;miq++){
        float2 tv = T[miq*32+c];
        float2 w = w32[((miq-15)*a)&31];
        acc += tv.x*w.x - tv.y*w.y;
      }
      y[t] = acc > 0.f ? acc : 0.f;
    }
    __syncthreads();
    // stage4: T2[mp,c] = sum_a y[a,c] e^{-2pi i mp a/32}  (T2 aliases T)
    for(int t=tid; t<480; t+=256){
      int mpq = t >> 5, c = t & 31;
      float2 acc = make_float2(0.f,0.f);
      for(int a=0;a<32;a++){
        float yv = y[a*32+c];
        float2 w = w32[((mpq-7)*a)&31];
        acc.x += yv*w.x; acc.y -= yv*w.y;
      }
      T2[mpq*32+c] = acc;
    }
    __syncthreads();
    // stage5: Xf[mp,np] -> accumulate into acc2 (LDS, races impossible: coef unique per (t,l))
    float wk = WL1[k]*TWO_PI_F;
    for(int t=tid; t<225; t+=256){
      int mpq = t/15, npq = t%15;
      int mp = mpq-7, np = npq-7;
      float2 acc = make_float2(0.f,0.f);
      for(int c=0;c<32;c++){
        float2 tv = T2[mpq*32+c];
        float2 w = w32[(np*c)&31];
        acc.x += tv.x*w.x + tv.y*w.y;
        acc.y += tv.y*w.x - tv.x*w.y;
      }
      acc.x *= (1.0f/1024.0f); acc.y *= (1.0f/1024.0f);
      int am = mp<0?-mp:mp, an = np<0?-np:np;
      int lmin = am>an?am:an;
      for(int l=lmin;l<8;l++){
        int c2 = 2*l+1; int o3 = off3d(l);
        int idx = (mp+l)*c2 + (np+l);
        float dv = D1[(size_t)o3*32 + (size_t)k*c2*c2 + idx];
        float g = wk*dv;
        float2 cur = acc2[o3+idx];
        cur.x += g*acc.x; cur.y += g*acc.y;
        acc2[o3+idx] = cur;
      }
    }
    __syncthreads();
  }
  for(int t=tid; t<680; t+=256)
    Fx2P[(size_t)t*1024 + b*64 + o] = acc2[t];
}

// K5: tiled transpose w2 [8192][192] -> w2t [192][8192]
__global__ void k_w2t(const float* __restrict__ w2, float* __restrict__ w2t){
  __shared__ float tile[32][33];
  int gx = blockIdx.x;            // io block (0..255)
  int gy = blockIdx.y;            // g block  (0..5)
  int tx = threadIdx.x & 31, ty = threadIdx.x >> 5;  // 32 x 8
  for(int r=0;r<32;r+=8)
    tile[ty+r][tx] = w2[(size_t)(gx*32+ty+r)*192 + gy*32+tx];
  __syncthreads();
  for(int r=0;r<32;r+=8)
    w2t[(size_t)(gy*32+ty+r)*8192 + gx*32+tx] = tile[tx][ty+r];
}

// K6: Fy2[coef][io] = sum_g w2t[g][io] * psi3[coef][g] — coalesced, 8 coefs/block
__global__ void __launch_bounds__(256) k_fy2(const float* __restrict__ cst,
                                             const float* __restrict__ w2t,
                                             float2* __restrict__ Fy2P){
  __shared__ float2 psiL[8*192];
  int cg  = blockIdx.x >> 5;      // coef group 0..84
  int iog = blockIdx.x & 31;      // io block
  int tid = threadIdx.x;
  int io  = iog*256 + tid;
  const float2* psi = (const float2*)(cst + OFF_PSI3) + (size_t)cg*8*192;
  for(int t=tid; t<1536; t+=256) psiL[t] = psi[t];
  __syncthreads();
  float2 acc[8];
  #pragma unroll
  for(int j=0;j<8;j++) acc[j] = make_float2(0.f,0.f);
  for(int g=0;g<192;g++){
    float w = w2t[(size_t)g*8192 + io];
    #pragma unroll
    for(int j=0;j<8;j++){
      float2 p = psiL[j*192+g];
      acc[j].x += w*p.x; acc[j].y += w*p.y;
    }
  }
  #pragma unroll
  for(int j=0;j<8;j++)
    Fy2P[((size_t)(cg*8+j))*8192 + io] = acc[j];
}

// K7: Fz2[coef][b,o] = sum_{kk,i} Fx2[.,kk][b,i] * conj(Fy2[.,kk][i,o]) — coalesced B, uniform A
__global__ void __launch_bounds__(256) k_fz2(const float2* __restrict__ Fx2P,
                                             const float2* __restrict__ Fy2P,
                                             float2* __restrict__ Fz2P){
  int coef = blockIdx.x;
  int l = 0; while(l<7 && off3d(l+1) <= coef) l++;
  int c = 2*l+1, o3 = off3d(l);
  int p = coef - o3; int mi = p/c, ni = p%c;
  int tid = threadIdx.x;
  int o = tid & 127;
  int bh = ((tid >> 7) << 3);
  bh = __builtin_amdgcn_readfirstlane(bh);
  float2 acc[8];
  #pragma unroll
  for(int j=0;j<8;j++) acc[j] = make_float2(0.f,0.f);
  for(int kk=0;kk<c;kk++){
    const float2* Ar = Fx2P + ((size_t)(o3 + mi*c + kk))*1024 + bh*64;
    const float2* Br = Fy2P + ((size_t)(o3 + ni*c + kk))*8192 + o;
    for(int i=0;i<64;i++){
      float2 bb = Br[(size_t)i*128];
      #pragma unroll
      for(int j=0;j<8;j++){
        float2 a = Ar[j*64+i];
        acc[j].x += a.x*bb.x + a.y*bb.y;
        acc[j].y += a.y*bb.x - a.x*bb.y;
      }
    }
  }
  #pragma unroll
  for(int j=0;j<8;j++)
    Fz2P[(size_t)coef*2048 + (size_t)(bh+j)*128 + o] = acc[j];
}

// K8: per (b,o): loop k2: S2 -> idft2(16x16) -> relu -> weighted mean -> feat[b,o]
__global__ void __launch_bounds__(256) k_slice2(const float* __restrict__ cst,
                                                const float2* __restrict__ Fz2P,
                                                float* __restrict__ featP){
  __shared__ float2 FzL[680];
  __shared__ float2 S2[225];
  __shared__ float2 TA[240];
  __shared__ float2 w16[16];
  __shared__ float red[256];
  int bo = blockIdx.x;
  int tid = threadIdx.x;
  if(tid < 16){ float ang = (TWO_PI_F/16.0f)*tid; w16[tid] = make_float2(cosf(ang), sinf(ang)); }
  for(int t=tid; t<680; t+=256) FzL[t] = Fz2P[(size_t)t*2048 + bo];
  __syncthreads();
  const float* D2  = cst + OFF_D2;
  const float* WL2 = cst + OFF_WL2;
  float part = 0.f;
  for(int k2=0;k2<16;k2++){
    if(tid < 225){
      int mi = tid/15, ni = tid%15;
      int m = mi-7, n = ni-7;
      int am = m<0?-m:m, an = n<0?-n:n;
      int lmin = am>an?am:an;
      float2 acc = make_float2(0.f,0.f);
      for(int l=lmin;l<8;l++){
        int c = 2*l+1; int o3 = off3d(l);
        float dv = D2[(size_t)o3*16 + (size_t)k2*c*c + (m+l)*c + (n+l)];
        float wgt = (float)(2*l+1)*dv;
        float2 fz = FzL[o3 + (m+l)*c + (n+l)];
        acc.x += wgt*fz.x; acc.y += wgt*fz.y;
      }
      S2[tid] = acc;
    }
    __syncthreads();
    if(tid < 240){
      int mi = tid >> 4, c = tid & 15;
      float2 acc = make_float2(0.f,0.f);
      for(int ni=0;ni<15;ni++){
        float2 sv = S2[mi*15+ni];
        float2 w = w16[((ni-7)*c)&15];
        acc.x += sv.x*w.x - sv.y*w.y;
        acc.y += sv.x*w.y + sv.y*w.x;
      }
      TA[mi*16+c] = acc;
    }
    __syncthreads();
    {
      int a = tid >> 4, c = tid & 15;
      float acc = 0.f;
      for(int mi=0;mi<15;mi++){
        float2 tv = TA[mi*16+c];
        float2 w = w16[((mi-7)*a)&15];
        acc += tv.x*w.x - tv.y*w.y;
      }
      if(acc > 0.f) part += WL2[k2]*acc;
    }
    __syncthreads();
  }
  red[tid] = part;
  __syncthreads();
  for(int s=128;s>0;s>>=1){ if(tid<s) red[tid]+=red[tid+s]; __syncthreads(); }
  if(tid==0) featP[bo] = red[0]*(1.0f/256.0f);
}

// K9: out[b,j] = sum_o feat[b,o]*lin_w[j,o] + lin_b[j]
__global__ void k_out(const float* __restrict__ featP, const float* __restrict__ lin_w,
                      const float* __restrict__ lin_b, float* __restrict__ out){
  int t = threadIdx.x;
  if(t < 160){
    int b = t/10, j = t%10;
    float acc = lin_b[j];
    for(int o=0;o<128;o++) acc += featP[b*128+o]*lin_w[j*128+o];
    out[t] = acc;
  }
}

extern "C" void kernel_launch(void* const* d_in, const int* in_sizes, int n_in,
                              void* d_out, int out_size, void* d_ws, size_t ws_size,
                              hipStream_t stream){
  const float* x     = (const float*)d_in[0];
  const float* w1    = (const float*)d_in[1];
  const float* w2    = (const float*)d_in[2];
  const float* lin_w = (const float*)d_in[3];
  const float* lin_b = (const float*)d_in[4];
  float* out = (float*)d_out;
  if(ws_size < WS_NEEDED) return;
  char* ws = (char*)d_ws;
  float2* xf1  = (float2*)(ws + OFS_XF1);
  float2* FxP  = (float2*)(ws + OFS_FX);
  float2* FyP  = (float2*)(ws + OFS_FY1);
  float2* Fx2P = (float2*)(ws + OFS_FX2);
  float2* Fy2P = (float2*)(ws + OFS_FY2);
  float2* Fz2P = (float2*)(ws + OFS_FZ2);
  float*  w2tP = (float*)(ws + OFS_W2T);     // overlaps Fz2 (dead before Fz2 written)
  float*  featP= (float*)(ws + OFS_FEAT);
  const float* cst = g_const;

  k_fft_alpha<<<2048, 128, 0, stream>>>(x, xf1);
  k_fx      <<<16,   256, 0, stream>>>(cst, xf1, FxP);
  k_fy1     <<<64,   256, 0, stream>>>(cst, w1, FyP);
  k_conv1   <<<1024, 256, 0, stream>>>(cst, FxP, FyP, Fx2P);
  k_w2t     <<<dim3(256,6), 256, 0, stream>>>(w2, w2tP);
  k_fy2     <<<2720, 256, 0, stream>>>(cst, w2tP, Fy2P);
  k_fz2     <<<680,  256, 0, stream>>>(Fx2P, Fy2P, Fz2P);
  k_slice2  <<<2048, 256, 0, stream>>>(cst, Fz2P, featP);
  k_out     <<<1,    256, 0, stream>>>(featP, lin_w, lin_b, out);
}

// Round 3
// 1284.751 us; speedup vs baseline: 3.2606x; 1.4530x over previous
//
#include <hip/hip_runtime.h>
#include <cmath>
#include <vector>
#include <algorithm>

// ---------------- constant table offsets (in floats) ----------------
enum : int {
  OFF_WIN  = 0,
  OFF_WL1  = 128,
  OFF_WL2  = 160,
  OFF_DCOL = 176,                // 256*128
  OFF_D1   = OFF_DCOL + 32768,   // 174592
  OFF_D2   = OFF_D1 + 174592,    // 10880
  OFF_PSI2 = OFF_D2 + 10880,     // 12288
  OFF_PSI3 = OFF_PSI2 + 12288,   // 261120
  CONST_TOTAL = OFF_PSI3 + 261120
};

// ---------------- workspace layout (bytes) ----------------
static constexpr size_t OFS_XF1  = 0;          // 16*128*31 c64
static constexpr size_t OFS_FX   = 507904;
static constexpr size_t OFS_FY1  = 540672;
static constexpr size_t OFS_FX2  = 671744;     // 1024*680 c64 (layout [b*64+i][coef])
static constexpr size_t OFS_FY2  = 6242304;    // 680*8192 c64
static constexpr size_t OFS_FZ2  = 50806784;   // 680*2048 c64
static constexpr size_t OFS_W2T  = OFS_FZ2;    // w2t overlaps Fz2 (dead before Fz2 written)
static constexpr size_t OFS_FEAT = 61947904;
static constexpr size_t WS_NEEDED = 61956096;

static inline int off3h(int l){ return (4*l*l*l - l)/3; }

// ---------------- host-side constant construction ----------------
namespace {

double fact_[32];
void init_fact(){ fact_[0]=1.0; for(int i=1;i<32;i++) fact_[i]=fact_[i-1]*i; }

void wigner_d(int l, double beta, double* d){
  int n = 2*l+1;
  double cb = std::cos(beta*0.5), sb = std::sin(beta*0.5);
  for(int r=0;r<n;r++){ int mp = r-l;
    for(int c=0;c<n;c++){ int m = c-l;
      double f = std::sqrt(fact_[l+mp]*fact_[l-mp]*fact_[l+m]*fact_[l-m]);
      int s0 = std::max(0, m-mp), s1 = std::min(l+m, l-mp);
      double sum = 0;
      for(int s=s0;s<=s1;s++){
        double t = (((mp-m+s)&1)? -1.0 : 1.0)
                 / (fact_[l+m-s]*fact_[s]*fact_[mp-m+s]*fact_[l-mp-s]);
        t *= std::pow(cb, (double)(2*l+m-mp-2*s)) * std::pow(sb, (double)(mp-m+2*s));
        sum += t;
      }
      d[r*n+c] = f*sum;
    }
  }
}

void dh_weights(int b, double* w){
  for(int j=0;j<2*b;j++){
    double s = 0;
    for(int l=0;l<b;l++) s += std::sin((2.0*j+1)*(2.0*l+1)*M_PI/(4.0*b))/(2.0*l+1);
    w[j] = (2.0/b)*std::sin(M_PI*(2.0*j+1)/(4.0*b))*s;
  }
}

float* g_const = nullptr;

struct ConstInit {
  ConstInit(){
    init_fact();
    std::vector<float> h((size_t)CONST_TOTAL, 0.0f);
    std::vector<double> tmp(31*31);
    { std::vector<double> w(128); dh_weights(64, w.data()); for(int i=0;i<128;i++) h[OFF_WIN+i]=(float)w[i]; }
    { std::vector<double> w(32);  dh_weights(16, w.data()); for(int i=0;i<32;i++)  h[OFF_WL1+i]=(float)w[i]; }
    { std::vector<double> w(16);  dh_weights(8,  w.data()); for(int i=0;i<16;i++)  h[OFF_WL2+i]=(float)w[i]; }
    for(int l=0;l<16;l++){ int n=2*l+1;
      for(int k=0;k<128;k++){
        wigner_d(l, M_PI*(2.0*k+1)/256.0, tmp.data());
        for(int mi=0;mi<n;mi++) h[OFF_DCOL + (size_t)(l*l+mi)*128 + k] = (float)tmp[mi*n + l];
      }
    }
    for(int l=0;l<16;l++){ int n=2*l+1;
      for(int k=0;k<32;k++){
        wigner_d(l, M_PI*(2.0*k+1)/64.0, tmp.data());
        for(int t=0;t<n*n;t++) h[OFF_D1 + (size_t)off3h(l)*32 + (size_t)k*n*n + t] = (float)tmp[t];
      }
    }
    for(int l=0;l<8;l++){ int n=2*l+1;
      for(int k=0;k<16;k++){
        wigner_d(l, M_PI*(2.0*k+1)/32.0, tmp.data());
        for(int t=0;t<n*n;t++) h[OFF_D2 + (size_t)off3h(l)*16 + (size_t)k*n*n + t] = (float)tmp[t];
      }
    }
    for(int l=0;l<16;l++){ int n=2*l+1;
      for(int i=0;i<3;i++){
        wigner_d(l, (i+1)*(M_PI/8.0)/3.0, tmp.data());
        for(int j=0;j<8;j++){
          double alpha = 2.0*M_PI*j/8.0;
          int g = i*8+j;
          for(int mi=0;mi<n;mi++){
            double d = tmp[mi*n + l];
            double th = (double)(mi-l)*alpha;
            size_t base = OFF_PSI2 + ((size_t)(l*l+mi)*24 + g)*2;
            h[base+0] = (float)( d*std::cos(th));
            h[base+1] = (float)(-d*std::sin(th));
          }
        }
      }
    }
    for(int l=0;l<8;l++){ int n=2*l+1;
      for(int i=0;i<3;i++){
        wigner_d(l, (i+1)*(M_PI/8.0)/3.0, tmp.data());
        for(int j=0;j<8;j++){
          double alpha = 2.0*M_PI*j/8.0;
          for(int kk=0;kk<8;kk++){
            double gamma = 2.0*M_PI*kk/8.0 - alpha;
            int g = (i*8+j)*8+kk;
            for(int mi=0;mi<n;mi++) for(int ni=0;ni<n;ni++){
              double d = tmp[mi*n+ni];
              double th = (double)(mi-l)*alpha + (double)(ni-l)*gamma;
              size_t base = OFF_PSI3 + (((size_t)off3h(l)+ (size_t)mi*n+ni)*192 + g)*2;
              h[base+0] = (float)( d*std::cos(th));
              h[base+1] = (float)(-d*std::sin(th));
            }
          }
        }
      }
    }
    hipMalloc((void**)&g_const, sizeof(float)*(size_t)CONST_TOTAL);
    hipMemcpy(g_const, h.data(), sizeof(float)*(size_t)CONST_TOTAL, hipMemcpyHostToDevice);
  }
};
ConstInit g_init_;

} // namespace

// ---------------- device helpers ----------------
__device__ __forceinline__ int off3d(int l){ return (4*l*l*l - l)/3; }
constexpr float TWO_PI_F = 6.28318530717958647692f;

// K1: xf1[b,k,m]
__global__ void k_fft_alpha(const float* __restrict__ x, float2* __restrict__ xf1){
  __shared__ float row[128];
  __shared__ float2 w128[128];
  int r = blockIdx.x;
  int t = threadIdx.x;
  row[t] = x[(size_t)r*128 + t];
  float ang = (TWO_PI_F/128.0f)*t;
  w128[t] = make_float2(cosf(ang), sinf(ang));
  __syncthreads();
  if(t < 31){
    int m = t - 15;
    float2 acc = make_float2(0.f,0.f);
    for(int a=0;a<128;a++){
      float2 w = w128[(m*a)&127];
      acc.x += row[a]*w.x;
      acc.y -= row[a]*w.y;
    }
    xf1[(size_t)r*31 + t] = acc;
  }
}

// K2: Fx[c2][b]
__global__ void k_fx(const float* __restrict__ cst, const float2* __restrict__ xf1,
                     float2* __restrict__ FxP){
  int idx = blockIdx.x*blockDim.x + threadIdx.x;
  int c2 = idx >> 4, b = idx & 15;
  int l = 0; while((l+1)*(l+1) <= c2) l++;
  int m = (c2 - l*l) - l;
  const float* W  = cst + OFF_WIN;
  const float* DC = cst + OFF_DCOL + (size_t)c2*128;
  float2 acc = make_float2(0.f,0.f);
  for(int k=0;k<128;k++){
    float wv = W[k]*DC[k];
    float2 xv = xf1[((size_t)b*128+k)*31 + (m+15)];
    acc.x += wv*xv.x; acc.y += wv*xv.y;
  }
  float s = TWO_PI_F/128.0f;
  FxP[(size_t)c2*16+b] = make_float2(acc.x*s, acc.y*s);
}

// K3: Fy1[c2][o]
__global__ void k_fy1(const float* __restrict__ cst, const float* __restrict__ w1,
                      float2* __restrict__ FyP){
  int idx = blockIdx.x*blockDim.x + threadIdx.x;
  int c2 = idx >> 6, o = idx & 63;
  const float2* psi = (const float2*)(cst + OFF_PSI2) + (size_t)c2*24;
  const float* w1r = w1 + (size_t)o*24;
  float2 acc = make_float2(0.f,0.f);
  for(int g=0;g<24;g++){
    float wv = w1r[g];
    float2 p = psi[g];
    acc.x += wv*p.x; acc.y += wv*p.y;
  }
  FyP[(size_t)c2*64+o] = acc;
}

// K4: fused first conv, Hermitian-halved.
// LDS map (37128 B total):
//   fz   : 0      2856 c64 (m>=0 half; row l: (l+1)x(2l+1))
//   S    : 22848  16x33 c64 (alias: FxL 256 c64, y 1024 f32, XfL 120 c64)
//   T    : 27072  16x33 c64 (alias: FyL 256 c64, T2 8x33 c64)
//   acc2 : 31296  680 c64
//   w32  : 36736  32 c64
//   o3T/oHT: 36992 2x17 int
__global__ void __launch_bounds__(256,4) k_conv1(const float* __restrict__ cst,
                                                 const float2* __restrict__ FxP,
                                                 const float2* __restrict__ FyP,
                                                 float2* __restrict__ Fx2P){
  __shared__ __align__(16) char ldsraw[37128];
  float2* fz   = (float2*)ldsraw;
  float2* S    = (float2*)(ldsraw + 22848);
  float2* T    = (float2*)(ldsraw + 27072);
  float2* acc2 = (float2*)(ldsraw + 31296);
  float2* w32  = (float2*)(ldsraw + 36736);
  int*    o3T  = (int*)(ldsraw + 36992);
  int*    oHT  = o3T + 17;
  float2* FxL  = S;
  float2* FyL  = T;
  float*  y    = (float*)S;
  float2* T2   = T;
  float2* XfL  = S;

  int b = blockIdx.x >> 6, o = blockIdx.x & 63;
  int tid = threadIdx.x;
  if(tid < 32){ float ang = (TWO_PI_F/32.0f)*tid; w32[tid] = make_float2(cosf(ang), sinf(ang)); }
  if(tid < 17){ int l = tid;
    o3T[l] = (4*l*l*l - l)/3;
    oHT[l] = l*(l-1)*(2*l-1)/3 + 3*l*(l-1)/2 + l;
  }
  FxL[tid] = FxP[(size_t)tid*16 + b];
  FyL[tid] = FyP[(size_t)tid*64 + o];
  for(int t=tid; t<680; t+=256) acc2[t] = make_float2(0.f,0.f);
  __syncthreads();
  // fz[l, m>=0, n] = Fx[l,m,b]*conj(Fy[l,n,o])
  for(int l=0;l<16;l++){
    int c = 2*l+1, cnt = (l+1)*c, base = oHT[l], l2 = l*l;
    for(int t=tid; t<cnt; t+=256){
      int mi = t/c, ni = t - mi*c;
      float2 fx = FxL[l2+l+mi], fy = FyL[l2+ni];
      fz[base+t] = make_float2(fx.x*fy.x + fx.y*fy.y, fx.y*fy.x - fx.x*fy.y);
    }
  }
  __syncthreads();
  const float* D1  = cst + OFF_D1;
  const float* WL1 = cst + OFF_WL1;
  for(int k=0;k<32;k++){
    // stage1: S[m,n] for m=0..15 only (S[-m,-n]=conj(S[m,n]))
    for(int t=tid; t<496; t+=256){
      int mi = t/31, niq = t - mi*31;
      int n = niq-15;
      int an = n<0?-n:n;
      int lmin = mi>an?mi:an;
      float2 acc = make_float2(0.f,0.f);
      for(int l=lmin;l<16;l++){
        int c = 2*l+1;
        float dv = D1[(size_t)o3T[l]*32 + k*c*c + (mi+l)*c + (n+l)];
        float2 fzv = fz[oHT[l] + mi*c + (n+l)];
        float wgt = (float)c * dv;
        acc.x += wgt*fzv.x; acc.y += wgt*fzv.y;
      }
      S[mi*33+niq] = acc;
    }
    __syncthreads();
    // stage2: T[m,c] = sum_n S[m,n] w^{nc}; pair c & c+16 via (-1)^n
    {
      int mi = tid >> 4, cp = tid & 15;
      float2 a0 = make_float2(0.f,0.f), a1 = make_float2(0.f,0.f);
      #pragma unroll
      for(int niq=0; niq<31; niq++){
        float2 sv = S[mi*33+niq];
        float2 w = w32[((niq-15)*cp)&31];
        float px = sv.x*w.x - sv.y*w.y;
        float py = sv.x*w.y + sv.y*w.x;
        a0.x += px; a0.y += py;
        if((niq&1)==0){ a1.x -= px; a1.y -= py; }
        else          { a1.x += px; a1.y += py; }
      }
      T[mi*33+cp]    = a0;
      T[mi*33+cp+16] = a1;
    }
    __syncthreads();
    // stage3: y[a,c] = T0.x + 2*sum_{m=1..15} Re(T[m,c] w^{ma}); 4 a-values per thread
    {
      int c = tid & 31, a0i = tid >> 5;   // a in {a0i, a0i+8, a0i+16, a0i+24}
      float t0x = T[c].x;
      float y0=0.f, y1=0.f, y2=0.f, y3=0.f;
      #pragma unroll
      for(int m=1;m<16;m++){
        float2 tv = T[m*33+c];
        float2 w = w32[(m*a0i)&31];
        float px = tv.x*w.x - tv.y*w.y;
        float py = tv.x*w.y + tv.y*w.x;
        y0 += px;
        int r = m & 3;
        if(r==0){ y1 += px; y3 += px; }
        else if(r==1){ y1 -= py; y3 += py; }
        else if(r==2){ y1 -= px; y3 -= px; }
        else { y1 += py; y3 -= py; }
        y2 += (m&1)? -px : px;
      }
      float v;
      v = t0x + 2.f*y0; y[ a0i     *32 + c] = v>0.f?v:0.f;
      v = t0x + 2.f*y1; y[(a0i+8 )*32 + c] = v>0.f?v:0.f;
      v = t0x + 2.f*y2; y[(a0i+16)*32 + c] = v>0.f?v:0.f;
      v = t0x + 2.f*y3; y[(a0i+24)*32 + c] = v>0.f?v:0.f;
    }
    __syncthreads();
    // stage4: T2[mp,c] for mp=0..7 (T2[-mp]=conj(T2[mp]) since y real)
    {
      int mp = tid >> 5, c4 = tid & 31;
      float2 acc = make_float2(0.f,0.f);
      #pragma unroll
      for(int a=0;a<32;a++){
        float yv = y[a*32+c4];
        float2 w = w32[(mp*a)&31];
        acc.x += yv*w.x;
        acc.y -= yv*w.y;
      }
      T2[mp*33+c4] = acc;
    }
    __syncthreads();
    // stage5: Xf[mp,np] for mp=0..7, np=-7..7
    if(tid < 120){
      int mpq = tid/15, npq = tid - mpq*15;
      int np = npq-7;
      float2 acc = make_float2(0.f,0.f);
      #pragma unroll
      for(int c=0;c<32;c++){
        float2 tv = T2[mpq*33+c];
        float2 w = w32[(np*c)&31];
        acc.x += tv.x*w.x + tv.y*w.y;
        acc.y += tv.y*w.x - tv.x*w.y;
      }
      XfL[mpq*15+npq] = make_float2(acc.x*(1.0f/1024.0f), acc.y*(1.0f/1024.0f));
    }
    __syncthreads();
    // accumulate into acc2 with Hermitian reconstruction for mp<0
    {
      float wk = WL1[k]*TWO_PI_F;
      if(tid < 225){
        int mi2 = tid/15, ni2 = tid - mi2*15;
        int mp = mi2-7, np = ni2-7;
        float2 xf;
        if(mp >= 0) xf = XfL[mp*15+ni2];
        else { float2 v = XfL[(-mp)*15 + (14-ni2)]; xf = make_float2(v.x, -v.y); }
        int am = mp<0?-mp:mp, an = np<0?-np:np;
        int lmin = am>an?am:an;
        for(int l=lmin;l<8;l++){
          int c2 = 2*l+1, o3 = o3T[l];
          int idx = (mp+l)*c2 + (np+l);
          float dv = D1[(size_t)o3*32 + k*c2*c2 + idx];
          float g = wk*dv;
          float2 cur = acc2[o3+idx];
          cur.x += g*xf.x; cur.y += g*xf.y;
          acc2[o3+idx] = cur;
        }
      }
    }
    __syncthreads();
  }
  // write out: Fx2 layout [b*64+o][coef] (coalesced)
  {
    size_t bo = (size_t)(b*64+o);
    for(int t=tid; t<680; t+=256)
      Fx2P[bo*680 + t] = acc2[t];
  }
}

// K5: tiled transpose w2 [8192][192] -> w2t [192][8192]
__global__ void k_w2t(const float* __restrict__ w2, float* __restrict__ w2t){
  __shared__ float tile[32][33];
  int gx = blockIdx.x;
  int gy = blockIdx.y;
  int tx = threadIdx.x & 31, ty = threadIdx.x >> 5;
  for(int r=0;r<32;r+=8)
    tile[ty+r][tx] = w2[(size_t)(gx*32+ty+r)*192 + gy*32+tx];
  __syncthreads();
  for(int r=0;r<32;r+=8)
    w2t[(size_t)(gy*32+ty+r)*8192 + gx*32+tx] = tile[tx][ty+r];
}

// K6: Fy2[coef][io] = sum_g w2t[g][io] * psi3[coef][g]
__global__ void __launch_bounds__(256) k_fy2(const float* __restrict__ cst,
                                             const float* __restrict__ w2t,
                                             float2* __restrict__ Fy2P){
  __shared__ float2 psiL[8*192];
  int cg  = blockIdx.x >> 5;
  int iog = blockIdx.x & 31;
  int tid = threadIdx.x;
  int io  = iog*256 + tid;
  const float2* psi = (const float2*)(cst + OFF_PSI3) + (size_t)cg*8*192;
  for(int t=tid; t<1536; t+=256) psiL[t] = psi[t];
  __syncthreads();
  float2 acc[8];
  #pragma unroll
  for(int j=0;j<8;j++) acc[j] = make_float2(0.f,0.f);
  for(int g=0;g<192;g++){
    float w = w2t[(size_t)g*8192 + io];
    #pragma unroll
    for(int j=0;j<8;j++){
      float2 p = psiL[j*192+g];
      acc[j].x += w*p.x; acc[j].y += w*p.y;
    }
  }
  #pragma unroll
  for(int j=0;j<8;j++)
    Fy2P[((size_t)(cg*8+j))*8192 + io] = acc[j];
}

// K7: Fz2[coef][b,o] = sum_{kk,i} Fx2[b,i][coef'] * conj(Fy2[coef''][i,o])
__global__ void __launch_bounds__(256) k_fz2(const float2* __restrict__ Fx2P,
                                             const float2* __restrict__ Fy2P,
                                             float2* __restrict__ Fz2P){
  int coef = blockIdx.x;
  int l = 0; while(l<7 && off3d(l+1) <= coef) l++;
  int c = 2*l+1, o3 = off3d(l);
  int p = coef - o3; int mi = p/c, ni = p%c;
  int tid = threadIdx.x;
  int o = tid & 127;
  int bh = ((tid >> 7) << 3);
  bh = __builtin_amdgcn_readfirstlane(bh);
  float2 acc[8];
  #pragma unroll
  for(int j=0;j<8;j++) acc[j] = make_float2(0.f,0.f);
  for(int kk=0;kk<c;kk++){
    int cA = o3 + mi*c + kk;
    int cB = o3 + ni*c + kk;
    const float2* Br = Fy2P + (size_t)cB*8192 + o;
    for(int i=0;i<64;i++){
      float2 bb = Br[(size_t)i*128];
      #pragma unroll
      for(int j=0;j<8;j++){
        float2 a = Fx2P[((size_t)((bh+j)*64+i))*680 + cA];
        acc[j].x += a.x*bb.x + a.y*bb.y;
        acc[j].y += a.y*bb.x - a.x*bb.y;
      }
    }
  }
  #pragma unroll
  for(int j=0;j<8;j++)
    Fz2P[(size_t)coef*2048 + (size_t)(bh+j)*128 + o] = acc[j];
}

// K8: per (b,o): loop k2: S2 -> idft2(16x16) -> relu -> weighted mean -> feat[b,o]
__global__ void __launch_bounds__(256) k_slice2(const float* __restrict__ cst,
                                                const float2* __restrict__ Fz2P,
                                                float* __restrict__ featP){
  __shared__ float2 FzL[680];
  __shared__ float2 S2[225];
  __shared__ float2 TA[240];
  __shared__ float2 w16[16];
  __shared__ float red[256];
  int bo = blockIdx.x;
  int tid = threadIdx.x;
  if(tid < 16){ float ang = (TWO_PI_F/16.0f)*tid; w16[tid] = make_float2(cosf(ang), sinf(ang)); }
  for(int t=tid; t<680; t+=256) FzL[t] = Fz2P[(size_t)t*2048 + bo];
  __syncthreads();
  const float* D2  = cst + OFF_D2;
  const float* WL2 = cst + OFF_WL2;
  float part = 0.f;
  for(int k2=0;k2<16;k2++){
    if(tid < 225){
      int mi = tid/15, ni = tid%15;
      int m = mi-7, n = ni-7;
      int am = m<0?-m:m, an = n<0?-n:n;
      int lmin = am>an?am:an;
      float2 acc = make_float2(0.f,0.f);
      for(int l=lmin;l<8;l++){
        int c = 2*l+1; int o3 = off3d(l);
        float dv = D2[(size_t)o3*16 + (size_t)k2*c*c + (m+l)*c + (n+l)];
        float wgt = (float)(2*l+1)*dv;
        float2 fzv = FzL[o3 + (m+l)*c + (n+l)];
        acc.x += wgt*fzv.x; acc.y += wgt*fzv.y;
      }
      S2[tid] = acc;
    }
    __syncthreads();
    if(tid < 240){
      int mi = tid >> 4, c = tid & 15;
      float2 acc = make_float2(0.f,0.f);
      for(int ni=0;ni<15;ni++){
        float2 sv = S2[mi*15+ni];
        float2 w = w16[((ni-7)*c)&15];
        acc.x += sv.x*w.x - sv.y*w.y;
        acc.y += sv.x*w.y + sv.y*w.x;
      }
      TA[mi*16+c] = acc;
    }
    __syncthreads();
    {
      int a = tid >> 4, c = tid & 15;
      float acc = 0.f;
      for(int mi=0;mi<15;mi++){
        float2 tv = TA[mi*16+c];
        float2 w = w16[((mi-7)*a)&15];
        acc += tv.x*w.x - tv.y*w.y;
      }
      if(acc > 0.f) part += WL2[k2]*acc;
    }
    __syncthreads();
  }
  red[tid] = part;
  __syncthreads();
  for(int s=128;s>0;s>>=1){ if(tid<s) red[tid]+=red[tid+s]; __syncthreads(); }
  if(tid==0) featP[bo] = red[0]*(1.0f/256.0f);
}

// K9: out[b,j]
__global__ void k_out(const float* __restrict__ featP, const float* __restrict__ lin_w,
                      const float* __restrict__ lin_b, float* __restrict__ out){
  int t = threadIdx.x;
  if(t < 160){
    int b = t/10, j = t%10;
    float acc = lin_b[j];
    for(int o=0;o<128;o++) acc += featP[b*128+o]*lin_w[j*128+o];
    out[t] = acc;
  }
}

extern "C" void kernel_launch(void* const* d_in, const int* in_sizes, int n_in,
                              void* d_out, int out_size, void* d_ws, size_t ws_size,
                              hipStream_t stream){
  const float* x     = (const float*)d_in[0];
  const float* w1    = (const float*)d_in[1];
  const float* w2    = (const float*)d_in[2];
  const float* lin_w = (const float*)d_in[3];
  const float* lin_b = (const float*)d_in[4];
  float* out = (float*)d_out;
  if(ws_size < WS_NEEDED) return;
  char* ws = (char*)d_ws;
  float2* xf1  = (float2*)(ws + OFS_XF1);
  float2* FxP  = (float2*)(ws + OFS_FX);
  float2* FyP  = (float2*)(ws + OFS_FY1);
  float2* Fx2P = (float2*)(ws + OFS_FX2);
  float2* Fy2P = (float2*)(ws + OFS_FY2);
  float2* Fz2P = (float2*)(ws + OFS_FZ2);
  float*  w2tP = (float*)(ws + OFS_W2T);
  float*  featP= (float*)(ws + OFS_FEAT);
  const float* cst = g_const;

  k_fft_alpha<<<2048, 128, 0, stream>>>(x, xf1);
  k_fx      <<<16,   256, 0, stream>>>(cst, xf1, FxP);
  k_fy1     <<<64,   256, 0, stream>>>(cst, w1, FyP);
  k_conv1   <<<1024, 256, 0, stream>>>(cst, FxP, FyP, Fx2P);
  k_w2t     <<<dim3(256,6), 256, 0, stream>>>(w2, w2tP);
  k_fy2     <<<2720, 256, 0, stream>>>(cst, w2tP, Fy2P);
  k_fz2     <<<680,  256, 0, stream>>>(Fx2P, Fy2P, Fz2P);
  k_slice2  <<<2048, 256, 0, stream>>>(cst, Fz2P, featP);
  k_out     <<<1,    256, 0, stream>>>(featP, lin_w, lin_b, out);
}